// Round 5
// baseline (147.610 us; speedup 1.0000x reference)
//
#include <hip/hip_runtime.h>
#include <hip/hip_bf16.h>

// Output row i (N = P*4 rows, D = 256 f32 each):
//   p = mapping[i]
//   last-of-group  <=> i == N-1 || mapping[i+1] != p
//   last  -> solvent_features[p]
//   else  -> monomer_features[i - p]   // monomer rank = i - (#lasts before i) = i - p
// Pure memory-bound gather (821 MB traffic, roofline ~130 us @ 6.3 TB/s).
// R5: 8 adjacent rows per wave-iter (8KB contiguous store, ~6KB contiguous
// mono read), mapping chunk index scalarized via readfirstlane so the 9
// mapping words become s_load through the constant cache.

typedef float f32x4 __attribute__((ext_vector_type(4)));

__global__ void __launch_bounds__(256)
separated_gnn_gather(const f32x4* __restrict__ mono,    // [P*3 * 64]
                     const f32x4* __restrict__ solv,    // [P   * 64]
                     const int*   __restrict__ mapping, // [N]
                     f32x4*       __restrict__ out,     // [N * 64]
                     int n_rows)
{
    const int lane = threadIdx.x & 63;
    // Provably wave-uniform wave id -> scalar mapping loads.
    const int wib  = __builtin_amdgcn_readfirstlane((int)(threadIdx.x >> 6));
    const int wpb  = (int)(blockDim.x >> 6);
    const long long wave    = (long long)blockIdx.x * wpb + wib;
    const long long n_waves = (long long)gridDim.x * wpb;

    const int n_chunks = n_rows >> 3;          // 8 adjacent rows per wave-iter

    for (long long g = wave; g < n_chunks; g += n_waves) {
        const int base = (int)(g << 3);        // first row of chunk

        // Mapping words for rows base..base+8 (9 values; uniform -> s_load).
        int m[9];
#pragma unroll
        for (int k = 0; k < 8; ++k) m[k] = mapping[base + k];
        m[8] = (base + 8 < n_rows) ? mapping[base + 8] : -1;  // end forces "last"

        // Per-row source addresses (general; chunking is processing layout only).
        const f32x4* src[8];
#pragma unroll
        for (int k = 0; k < 8; ++k) {
            const int i = base + k;
            const int p = m[k];
            const bool last = (m[k + 1] != p);
            src[k] = last ? (solv + (long long)p * 64)
                          : (mono + (long long)(i - p) * 64);
        }

        // 8 independent 1KB loads (mono rows contiguous across the chunk).
        f32x4 v[8];
#pragma unroll
        for (int k = 0; k < 8; ++k)
            v[k] = __builtin_nontemporal_load(src[k] + lane);

        // 8KB contiguous store.
        f32x4* o = out + (long long)base * 64 + lane;
#pragma unroll
        for (int k = 0; k < 8; ++k)
            __builtin_nontemporal_store(v[k], o + k * 64);
    }

    // Generic tail for n_rows % 8 != 0 (empty for N = 400000).
    const long long tail_start = (long long)n_chunks * 8 * 64;
    const long long total      = (long long)n_rows * 64;
    const long long stride     = (long long)gridDim.x * blockDim.x;
    for (long long t = tail_start + (long long)blockIdx.x * blockDim.x + threadIdx.x;
         t < total; t += stride) {
        const int i = (int)(t >> 6);
        const int c = (int)(t & 63);
        const int p = mapping[i];
        const bool last = (i + 1 == n_rows) || (mapping[i + 1] != p);
        const f32x4* s = last ? (solv + (long long)p * 64)
                              : (mono + (long long)(i - p) * 64);
        __builtin_nontemporal_store(__builtin_nontemporal_load(s + c), out + t);
    }
}

extern "C" void kernel_launch(void* const* d_in, const int* in_sizes, int n_in,
                              void* d_out, int out_size, void* d_ws, size_t ws_size,
                              hipStream_t stream)
{
    const f32x4* mono    = (const f32x4*)d_in[0];   // monomer_features  [P*3, 256] f32
    const f32x4* solv    = (const f32x4*)d_in[1];   // solvent_features  [P,   256] f32
    const int*   mapping = (const int*)d_in[2];     // polymer_mapping   [N] int32
    f32x4*       out     = (f32x4*)d_out;           // [N, 256] f32

    const int n_rows = in_sizes[2];                 // N = 400000

    const int block = 256;
    const int grid  = 2048;                         // 8192 waves, grid-stride chunks

    separated_gnn_gather<<<grid, block, 0, stream>>>(mono, solv, mapping, out, n_rows);
}

// Round 6
// 145.845 us; speedup vs baseline: 1.0121x; 1.0121x over previous
//
#include <hip/hip_runtime.h>
#include <hip/hip_bf16.h>

// Output row i (N = P*4 rows, D = 256 f32 each):
//   p = mapping[i]
//   last-of-group  <=> i == N-1 || mapping[i+1] != p
//   last  -> solvent_features[p]
//   else  -> monomer_features[i - p]   // monomer rank = i - (#lasts before i) = i - p
// Pure memory-bound gather (821 MB traffic, roofline ~130 us @ 6.3 TB/s).
// R6: isolate the R5 confound — 8 adjacent rows per wave-iter but with R4's
// lane-broadcast VECTOR mapping loads (no readfirstlane/s_load serialization).
// Only one variable changed vs R4 (chunk 4 -> 8).

typedef float f32x4 __attribute__((ext_vector_type(4)));

#define CHUNK 8

__global__ void __launch_bounds__(256)
separated_gnn_gather(const f32x4* __restrict__ mono,    // [P*3 * 64]
                     const f32x4* __restrict__ solv,    // [P   * 64]
                     const int*   __restrict__ mapping, // [N]
                     f32x4*       __restrict__ out,     // [N * 64]
                     int n_rows)
{
    const int lane    = threadIdx.x & 63;
    const long long wave    = ((long long)blockIdx.x * blockDim.x + threadIdx.x) >> 6;
    const long long n_waves = ((long long)gridDim.x * blockDim.x) >> 6;

    const int n_chunks = n_rows / CHUNK;       // CHUNK adjacent rows per wave-iter

    for (long long g = wave; g < n_chunks; g += n_waves) {
        const int base = (int)(g * CHUNK);     // first row of chunk

        // Mapping words for rows base..base+CHUNK (lane-broadcast vector loads,
        // L1 same-address broadcast; issued together, overlap in VMEM queue).
        int m[CHUNK + 1];
#pragma unroll
        for (int k = 0; k < CHUNK; ++k) m[k] = mapping[base + k];
        m[CHUNK] = (base + CHUNK < n_rows) ? mapping[base + CHUNK] : -1; // end => "last"

        // Per-row source addresses (general per-row logic; chunking is layout only).
        const f32x4* src[CHUNK];
#pragma unroll
        for (int k = 0; k < CHUNK; ++k) {
            const int i = base + k;
            const int p = m[k];
            const bool last = (m[k + 1] != p);
            src[k] = last ? (solv + (long long)p * 64)
                          : (mono + (long long)(i - p) * 64);
        }

        // CHUNK independent 1KB loads (mono rows contiguous across the chunk).
        f32x4 v[CHUNK];
#pragma unroll
        for (int k = 0; k < CHUNK; ++k)
            v[k] = __builtin_nontemporal_load(src[k] + lane);

        // CHUNK KB contiguous store.
        f32x4* o = out + (long long)base * 64 + lane;
#pragma unroll
        for (int k = 0; k < CHUNK; ++k)
            __builtin_nontemporal_store(v[k], o + k * 64);
    }

    // Generic tail for n_rows % CHUNK != 0 (empty for N = 400000).
    const long long tail_start = (long long)n_chunks * CHUNK * 64;
    const long long total      = (long long)n_rows * 64;
    const long long stride     = (long long)gridDim.x * blockDim.x;
    for (long long t = tail_start + (long long)blockIdx.x * blockDim.x + threadIdx.x;
         t < total; t += stride) {
        const int i = (int)(t >> 6);
        const int c = (int)(t & 63);
        const int p = mapping[i];
        const bool last = (i + 1 == n_rows) || (mapping[i + 1] != p);
        const f32x4* s = last ? (solv + (long long)p * 64)
                              : (mono + (long long)(i - p) * 64);
        __builtin_nontemporal_store(__builtin_nontemporal_load(s + c), out + t);
    }
}

extern "C" void kernel_launch(void* const* d_in, const int* in_sizes, int n_in,
                              void* d_out, int out_size, void* d_ws, size_t ws_size,
                              hipStream_t stream)
{
    const f32x4* mono    = (const f32x4*)d_in[0];   // monomer_features  [P*3, 256] f32
    const f32x4* solv    = (const f32x4*)d_in[1];   // solvent_features  [P,   256] f32
    const int*   mapping = (const int*)d_in[2];     // polymer_mapping   [N] int32
    f32x4*       out     = (f32x4*)d_out;           // [N, 256] f32

    const int n_rows = in_sizes[2];                 // N = 400000

    const int block = 256;
    const int grid  = 2048;                         // 8192 waves, grid-stride chunks

    separated_gnn_gather<<<grid, block, 0, stream>>>(mono, solv, mapping, out, n_rows);
}